// Round 1
// baseline (382.553 us; speedup 1.0000x reference)
//
#include <hip/hip_runtime.h>

// ---------------------------------------------------------------------------
// STN forward, fp32 baseline.
//  K1: conv1(7x7,1->8,SAME) + maxpool2 + relu  -> xs1 [288][Bc] in ws
//  K2: conv2(5x5,8->10,SAME) + maxpool2 + relu + FC(90->32->6) -> theta [6][B]
//  K3: affine grid + bilinear sample (scipy/jax 'reflect' on integer indices)
// ---------------------------------------------------------------------------

__device__ __forceinline__ int refl12(int i) {
    // jax/scipy map_coordinates mode='reflect' (half-sample symmetric), n=12.
    int r = i % 24;
    if (r < 0) r += 24;
    return (r < 12) ? r : 23 - r;
}

__global__ __launch_bounds__(64, 1) void k1_conv1(
    const float* __restrict__ x,     // (B,144)
    const float* __restrict__ k1w,   // (7,7,1,8)
    const float* __restrict__ bc1,   // (8)
    float* __restrict__ xs1,         // [288][stride]
    int img0, int stride, int imgEnd, int B)
{
    __shared__ float xl[64 * 145];   // stride 145: 17*i mod 32 -> all banks
    const int tid = threadIdx.x;
    const long long imgbase = (long long)img0 + (long long)blockIdx.x * 64;

    // cooperative, coalesced float4 load of 64 images
    const float4* xg = (const float4*)(x + imgbase * 144);
    #pragma unroll 1
    for (int k = tid; k < 2304; k += 64) {
        int il = k / 36;
        int r  = k - il * 36;
        float4 v = make_float4(0.f, 0.f, 0.f, 0.f);
        if (imgbase + il < B) v = xg[(size_t)il * 36 + r];
        float* dst = &xl[il * 145 + r * 4];
        dst[0] = v.x; dst[1] = v.y; dst[2] = v.z; dst[3] = v.w;
    }
    __syncthreads();

    const float* myx = &xl[tid * 145];
    const int img = (int)(imgbase + tid);

    float bias[8];
    #pragma unroll
    for (int c = 0; c < 8; ++c) bias[c] = bc1[c];

    float hp[6][8];

    #pragma unroll 1
    for (int yp = 0; yp < 6; ++yp) {
        #pragma unroll 1
        for (int half = 0; half < 2; ++half) {
            const int y = 2 * yp + half;
            float acc[12][8];
            #pragma unroll
            for (int xx = 0; xx < 12; ++xx)
                #pragma unroll
                for (int c = 0; c < 8; ++c) acc[xx][c] = bias[c];

            #pragma unroll 1
            for (int ky = 0; ky < 7; ++ky) {
                const int iy = y + ky - 3;
                if (iy < 0 || iy >= 12) continue;      // uniform branch
                float row[18];                          // zero-padded input row
                #pragma unroll
                for (int j = 0; j < 18; ++j) {
                    const int ix = j - 3;
                    row[j] = (ix >= 0 && ix < 12) ? myx[iy * 12 + ix] : 0.f;
                }
                const float* wbase = k1w + ky * 56;     // uniform -> s_load
                #pragma unroll
                for (int kx = 0; kx < 7; ++kx) {
                    float w8[8];
                    #pragma unroll
                    for (int c = 0; c < 8; ++c) w8[c] = wbase[kx * 8 + c];
                    #pragma unroll
                    for (int xx = 0; xx < 12; ++xx) {
                        const float xv = row[xx + kx];
                        #pragma unroll
                        for (int c = 0; c < 8; ++c)
                            acc[xx][c] = fmaf(xv, w8[c], acc[xx][c]);
                    }
                }
            }
            if (half == 0) {
                #pragma unroll
                for (int xp = 0; xp < 6; ++xp)
                    #pragma unroll
                    for (int c = 0; c < 8; ++c)
                        hp[xp][c] = fmaxf(acc[2*xp][c], acc[2*xp+1][c]);
            } else {
                #pragma unroll
                for (int xp = 0; xp < 6; ++xp)
                    #pragma unroll
                    for (int c = 0; c < 8; ++c) {
                        float m = fmaxf(hp[xp][c],
                                        fmaxf(acc[2*xp][c], acc[2*xp+1][c]));
                        m = fmaxf(m, 0.f);
                        if (img < imgEnd) {
                            const int v = yp * 48 + xp * 8 + c;
                            xs1[(size_t)v * stride + (img - img0)] = m;
                        }
                    }
            }
        }
    }
}

__global__ __launch_bounds__(256, 1) void k2_theta(
    const float* __restrict__ xs1,   // [288][stride]
    const float* __restrict__ k2w,   // (5,5,8,10)
    const float* __restrict__ bc2,   // (10)
    const float* __restrict__ W1,    // (90,32)
    const float* __restrict__ b1,    // (32)
    const float* __restrict__ W2,    // (32,6)
    const float* __restrict__ b2,    // (6)
    float* __restrict__ theta,       // [6][B]
    int img0, int cur, int stride, int B)
{
    const int li = blockIdx.x * 256 + threadIdx.x;
    if (li >= cur) return;
    const int img = img0 + li;
    const float* __restrict__ xin = xs1 + li;

    float fc1[32];
    #pragma unroll
    for (int j = 0; j < 32; ++j) fc1[j] = b1[j];

    float pool[3][10];

    #pragma unroll 1
    for (int pr = 0; pr < 3; ++pr) {
        #pragma unroll 1
        for (int half = 0; half < 2; ++half) {
            const int Y = 2 * pr + half;
            float acc[6][10];
            #pragma unroll
            for (int xx = 0; xx < 6; ++xx)
                #pragma unroll
                for (int c = 0; c < 10; ++c) acc[xx][c] = bc2[c];

            #pragma unroll 1
            for (int ky = 0; ky < 5; ++ky) {
                const int iy = Y + ky - 2;
                if (iy < 0 || iy >= 6) continue;       // uniform branch
                float row[48];                          // one xs1 row (6x8)
                #pragma unroll
                for (int j = 0; j < 48; ++j)
                    row[j] = xin[(size_t)(iy * 48 + j) * stride];  // coalesced
                const float* wk = k2w + ky * 400;
                #pragma unroll
                for (int kx = 0; kx < 5; ++kx) {
                    #pragma unroll
                    for (int ci = 0; ci < 8; ++ci) {
                        const float* w10 = wk + (kx * 8 + ci) * 10;
                        float w[10];
                        #pragma unroll
                        for (int c = 0; c < 10; ++c) w[c] = w10[c];
                        #pragma unroll
                        for (int xx = 0; xx < 6; ++xx) {
                            const int ix = xx + kx - 2;
                            if (ix < 0 || ix >= 6) continue;  // compile-time
                            const float xv = row[ix * 8 + ci];
                            #pragma unroll
                            for (int c = 0; c < 10; ++c)
                                acc[xx][c] = fmaf(xv, w[c], acc[xx][c]);
                        }
                    }
                }
            }
            if (half == 0) {
                #pragma unroll
                for (int px = 0; px < 3; ++px)
                    #pragma unroll
                    for (int c = 0; c < 10; ++c)
                        pool[px][c] = fmaxf(acc[2*px][c], acc[2*px+1][c]);
            } else {
                #pragma unroll
                for (int px = 0; px < 3; ++px)
                    #pragma unroll
                    for (int c = 0; c < 10; ++c) {
                        float m = fmaxf(pool[px][c],
                                        fmaxf(acc[2*px][c], acc[2*px+1][c]));
                        m = fmaxf(m, 0.f);                 // relu -> xs2 value
                        const int v = pr * 30 + px * 10 + c;
                        const float* w1r = W1 + v * 32;    // uniform -> s_load
                        #pragma unroll
                        for (int j = 0; j < 32; ++j)
                            fc1[j] = fmaf(m, w1r[j], fc1[j]);
                    }
            }
        }
    }

    float th[6];
    #pragma unroll
    for (int t = 0; t < 6; ++t) th[t] = b2[t];
    #pragma unroll
    for (int j = 0; j < 32; ++j) {
        const float h = fmaxf(fc1[j], 0.f);
        const float* w2r = W2 + j * 6;
        #pragma unroll
        for (int t = 0; t < 6; ++t) th[t] = fmaf(h, w2r[t], th[t]);
    }
    const float inv = 1.0f / (1.0f + 1e-5f);
    #pragma unroll
    for (int t = 0; t < 6; ++t)
        theta[(size_t)t * B + img] = th[t] * inv;
}

__global__ __launch_bounds__(256, 1) void k3_sample(
    const float* __restrict__ x,       // (B,144)
    const float* __restrict__ theta,   // [6][B]
    float* __restrict__ out,           // (B,144)
    int B)
{
    const long long gid = (long long)blockIdx.x * 256 + threadIdx.x;
    const long long total = (long long)B * 144;
    if (gid >= total) return;
    const int img = (int)(gid / 144);
    const int p = (int)(gid - (long long)img * 144);
    const int i = p / 12;
    const int j = p - i * 12;

    const float t0 = theta[img];
    const float t1 = theta[(size_t)B + img];
    const float t2 = theta[(size_t)2 * B + img];
    const float t3 = theta[(size_t)3 * B + img];
    const float t4 = theta[(size_t)4 * B + img];
    const float t5 = theta[(size_t)5 * B + img];

    const float step = 2.0f / 11.0f;
    const float xn = -1.0f + j * step;
    const float yn = -1.0f + i * step;
    const float sx = t0 * xn + t1 * yn + t2;
    const float sy = t3 * xn + t4 * yn + t5;
    const float px = (sx + 1.0f) * 5.5f;
    const float py = (sy + 1.0f) * 5.5f;

    const float fy = floorf(py), fx = floorf(px);
    const float wy = py - fy,    wx = px - fx;
    const int ly = (int)fy, lx = (int)fx;
    const int y0 = refl12(ly),     y1 = refl12(ly + 1);
    const int x0 = refl12(lx),     x1 = refl12(lx + 1);

    const float* xi = x + (size_t)img * 144;
    const float v00 = xi[y0 * 12 + x0];
    const float v01 = xi[y0 * 12 + x1];
    const float v10 = xi[y1 * 12 + x0];
    const float v11 = xi[y1 * 12 + x1];

    const float r0 = v00 + wx * (v01 - v00);
    const float r1 = v10 + wx * (v11 - v10);
    out[gid] = r0 + wy * (r1 - r0);
}

extern "C" void kernel_launch(void* const* d_in, const int* in_sizes, int n_in,
                              void* d_out, int out_size, void* d_ws, size_t ws_size,
                              hipStream_t stream)
{
    const float* x   = (const float*)d_in[0];
    const float* k1w = (const float*)d_in[1];
    const float* bc1 = (const float*)d_in[2];
    const float* k2w = (const float*)d_in[3];
    const float* bc2 = (const float*)d_in[4];
    const float* W1  = (const float*)d_in[5];
    const float* b1  = (const float*)d_in[6];
    const float* W2  = (const float*)d_in[7];
    const float* b2  = (const float*)d_in[8];
    float* out = (float*)d_out;
    const int B = in_sizes[0] / 144;

    float* theta = (float*)d_ws;
    float* xs1 = theta + (size_t)6 * B;

    const size_t theta_bytes = (size_t)6 * B * 4;
    const size_t avail = (ws_size > theta_bytes) ? (ws_size - theta_bytes) : 0;
    long long bc_ll = (long long)(avail / (288 * 4));
    int Bc = (bc_ll >= (long long)B) ? B : (int)bc_ll;
    Bc &= ~255;                  // multiple of 256 (K1 needs x64, K2 x256)
    if (Bc <= 0) Bc = 256;       // last resort; assumes ws_size is sane

    for (int img0 = 0; img0 < B; img0 += Bc) {
        const int cur = (B - img0 < Bc) ? (B - img0) : Bc;
        const int imgEnd = img0 + cur;
        const int nb1 = (cur + 63) / 64;
        hipLaunchKernelGGL(k1_conv1, dim3(nb1), dim3(64), 0, stream,
                           x, k1w, bc1, xs1, img0, Bc, imgEnd, B);
        const int nb2 = (cur + 255) / 256;
        hipLaunchKernelGGL(k2_theta, dim3(nb2), dim3(256), 0, stream,
                           xs1, k2w, bc2, W1, b1, W2, b2, theta,
                           img0, cur, Bc, B);
    }
    const long long total = (long long)B * 144;
    const int nb3 = (int)((total + 255) / 256);
    hipLaunchKernelGGL(k3_sample, dim3(nb3), dim3(256), 0, stream,
                       x, theta, out, B);
}

// Round 3
// 249.289 us; speedup vs baseline: 1.5346x; 1.5346x over previous
//
#include <hip/hip_runtime.h>

typedef __attribute__((ext_vector_type(8))) short bfrag;   // 8 x bf16
typedef __attribute__((ext_vector_type(4))) float facc;    // mfma accumulator

__device__ __forceinline__ short f2bf(float f) {
    unsigned u = __float_as_uint(f);
    u += 0x7FFFu + ((u >> 16) & 1u);          // round-to-nearest-even
    return (short)(u >> 16);
}
__device__ __forceinline__ int refl12(int i) {
    int r = i % 24; if (r < 0) r += 24; return (r < 12) ? r : 23 - r;
}

__device__ __forceinline__ facc mfma16(bfrag a, bfrag b, facc c) {
    return __builtin_amdgcn_mfma_f32_16x16x32_bf16(a, b, c, 0, 0, 0);
}

// ws layout (element offsets in shorts)
#define WB1_E 0                         // [1152][160] bf16
#define WB2_E 184320                    // [576][288]  bf16
#define W1T_E 350208                    // [32][96]    bf16
#define W2T_E 353280                    // [16][32]    bf16
#define XS1_E 353792                    // [B][288]    bf16
// theta (float) follows at byte offset 707584 + B*576

// ---------------------------------------------------------------------------
// K0: expand conv/FC weights into GEMM-friendly bf16 matrices in ws
// ---------------------------------------------------------------------------
__global__ void k0_build(const float* __restrict__ k1w, const float* __restrict__ k2w,
                         const float* __restrict__ W1, const float* __restrict__ W2,
                         short* __restrict__ ws)
{
    const int NW1 = 1152 * 160, NW2 = 576 * 288, NT1 = 32 * 96, NT2 = 16 * 32;
    const int total = NW1 + NW2 + NT1 + NT2;
    for (int q = blockIdx.x * blockDim.x + threadIdx.x; q < total;
         q += gridDim.x * blockDim.x) {
        float val = 0.f;
        short* dst;
        if (q < NW1) {
            // Wbig1[n][kk]: n = p1*32 + (hy*2+hx)*8 + c ; kk = input pixel
            int n = q / 160, kk = q - n * 160;
            dst = ws + WB1_E + q;
            int p1 = n >> 5, r = n & 31;
            int hy = (r >> 4) & 1, hx = (r >> 3) & 1, c = r & 7;
            int yp = p1 / 6, xp = p1 - yp * 6;
            int y = 2 * yp + hy, xo = 2 * xp + hx;
            if (kk < 144) {
                int yi = kk / 12, xi = kk - yi * 12;
                int ky = yi - y + 3, kx = xi - xo + 3;
                if (ky >= 0 && ky < 7 && kx >= 0 && kx < 7)
                    val = k1w[(ky * 7 + kx) * 8 + c];
            }
        } else if (q < NW1 + NW2) {
            // Wbig2[n2][k2]: n2 = q2*64 + g*16 + c2 ; k2 = p1*8 + c1
            int qq = q - NW1;
            int n = qq / 288, k2 = qq - n * 288;
            dst = ws + WB2_E + qq;
            int q2 = n >> 6, r = n & 63, g = r >> 4, c2 = r & 15;
            int gy = g >> 1, gx = g & 1;
            int qy = q2 / 3, qx = q2 - qy * 3;
            int Y = 2 * qy + gy, X = 2 * qx + gx;
            int p1 = k2 >> 3, c1 = k2 & 7;
            int yp = p1 / 6, xp = p1 - yp * 6;
            int ky = yp - Y + 2, kx = xp - X + 2;
            if (c2 < 10 && ky >= 0 && ky < 5 && kx >= 0 && kx < 5)
                val = k2w[((ky * 5 + kx) * 8 + c1) * 10 + c2];
        } else if (q < NW1 + NW2 + NT1) {
            int qq = q - NW1 - NW2;
            int j = qq / 96, k = qq - j * 96;
            dst = ws + W1T_E + qq;
            if (k < 90) val = W1[k * 32 + j];
        } else {
            int qq = q - NW1 - NW2 - NT1;
            int t = qq / 32, k = qq - t * 32;
            dst = ws + W2T_E + qq;
            if (t < 6) val = W2[k * 6 + t];
        }
        *dst = f2bf(val);
    }
}

// ---------------------------------------------------------------------------
// K1: GEMM1  out = x(Bx144) @ Wbig1(144x1152), fused maxpool+relu -> xs1 bf16
//     block = 512 thr (8 waves = 2 Mgrp x 4 Ngrp), M-tile 128, A in registers
// ---------------------------------------------------------------------------
__global__ __launch_bounds__(512) void k1_gemm(
    const float* __restrict__ x, const short* __restrict__ wb1,
    const float* __restrict__ bc1, short* __restrict__ xs1, int B)
{
    const int tid = threadIdx.x;
    const int l = tid & 63, w = tid >> 6;
    const int mg = w >> 2, ng = w & 3;
    const int lr = l & 15, lg = l >> 4;
    const int mwave = blockIdx.x * 128 + mg * 64;

    // A fragments: this wave's 64 image-rows x K=160 (144 real, rest zero)
    bfrag a[4][5];
    #pragma unroll
    for (int ms = 0; ms < 4; ++ms) {
        int img = mwave + ms * 16 + lr;
        if (img >= B) img = B - 1;
        const float* row = x + (size_t)img * 144;
        #pragma unroll
        for (int t = 0; t < 5; ++t) {
            const int k = t * 32 + lg * 8;
            bfrag f = {0, 0, 0, 0, 0, 0, 0, 0};
            if (k < 144) {
                float4 u0 = *(const float4*)(row + k);
                float4 u1 = *(const float4*)(row + k + 4);
                f[0] = f2bf(u0.x); f[1] = f2bf(u0.y);
                f[2] = f2bf(u0.z); f[3] = f2bf(u0.w);
                f[4] = f2bf(u1.x); f[5] = f2bf(u1.y);
                f[6] = f2bf(u1.z); f[7] = f2bf(u1.w);
            }
            a[ms][t] = f;
        }
    }
    const float bcv = bc1[l & 7];

    #pragma unroll 1
    for (int j = 0; j < 9; ++j) {
        const int p1 = j * 4 + ng;           // pooled position, 0..35
        facc acc[4][2];
        #pragma unroll
        for (int ms = 0; ms < 4; ++ms)
            #pragma unroll
            for (int nt = 0; nt < 2; ++nt)
                acc[ms][nt] = (facc){0.f, 0.f, 0.f, 0.f};

        #pragma unroll
        for (int nt = 0; nt < 2; ++nt)
            #pragma unroll
            for (int t = 0; t < 5; ++t) {
                const bfrag b = *(const bfrag*)(
                    wb1 + (size_t)(p1 * 32 + nt * 16 + lr) * 160 + t * 32 + lg * 8);
                #pragma unroll
                for (int ms = 0; ms < 4; ++ms)
                    acc[ms][nt] = mfma16(a[ms][t], b, acc[ms][nt]);
            }

        // pool (hy: tile0 vs tile1, hx: col c vs c+8) + bias + relu + store
        #pragma unroll
        for (int ms = 0; ms < 4; ++ms) {
            #pragma unroll
            for (int i = 0; i < 4; ++i) {
                float p = fmaxf(acc[ms][0][i], acc[ms][1][i]);
                p = fmaxf(p, __shfl_xor(p, 8));
                p = fmaxf(p + bcv, 0.f);
                if ((l & 15) < 8) {
                    int img = mwave + ms * 16 + lg * 4 + i;
                    if (img < B)
                        xs1[(size_t)img * 288 + p1 * 8 + (l & 7)] = f2bf(p);
                }
            }
        }
    }
}

// ---------------------------------------------------------------------------
// K2: GEMM2 (xs1 @ Wbig2, pool+relu) + FC1 + FC2 -> theta[B][6]
//     block = 512 thr, M-tile 128; A2/XS2/FC1 in XOR-swizzled LDS
// ---------------------------------------------------------------------------
__global__ __launch_bounds__(512) void k2_gemm(
    const short* __restrict__ xs1, const short* __restrict__ wb2,
    const short* __restrict__ w1t, const short* __restrict__ w2t,
    const float* __restrict__ bc2, const float* __restrict__ b1,
    const float* __restrict__ b2, float* __restrict__ theta, int B)
{
    __shared__ short A2[128 * 320];   // [m][320] (288 real k), 16B-block XOR swizzle
    __shared__ short XS2[128 * 128];  // [m][128] (90 real k)
    __shared__ short FC1[128 * 64];   // [m][64]  (32 real k)

    const int tid = threadIdx.x;
    const int l = tid & 63, w = tid >> 6;
    const int lr = l & 15, lg = l >> 4;
    const long long blkbase = (long long)blockIdx.x * 128;

    // stage A2 (swizzled), zero XS2 pad
    for (int q = tid; q < 4608; q += 512) {
        int m = q / 36, kb = q - m * 36;
        long long img = blkbase + m;
        if (img >= B) img = B - 1;
        bfrag v = *(const bfrag*)(xs1 + img * 288 + kb * 8);
        *(bfrag*)&A2[m * 320 + ((kb ^ (m & 7)) << 3)] = v;
    }
    for (int q = tid; q < 2048; q += 512) {
        bfrag z = {0, 0, 0, 0, 0, 0, 0, 0};
        *(bfrag*)&XS2[q * 8] = z;
    }
    __syncthreads();

    const int mg = w >> 2, ng = w & 3;
    const int c2 = lr;
    const float bcv2 = (c2 < 10) ? bc2[c2] : 0.f;

    #pragma unroll 1
    for (int jj = 0; jj < 3; ++jj) {
        const int q2 = jj * 4 + ng;          // pooled output position, 0..8
        if (q2 < 9) {
            facc acc[4][4];
            #pragma unroll
            for (int ms = 0; ms < 4; ++ms)
                #pragma unroll
                for (int g = 0; g < 4; ++g)
                    acc[ms][g] = (facc){0.f, 0.f, 0.f, 0.f};

            #pragma unroll
            for (int t = 0; t < 9; ++t) {
                bfrag av[4];
                #pragma unroll
                for (int ms = 0; ms < 4; ++ms) {
                    int m = mg * 64 + ms * 16 + lr;
                    av[ms] = *(const bfrag*)&A2[m * 320 + (((t * 4 + lg) ^ (m & 7)) << 3)];
                }
                #pragma unroll
                for (int g = 0; g < 4; ++g) {
                    // B row index MUST match k0_build: n2 = q2*64 + g*16 + c2
                    const bfrag bv = *(const bfrag*)(
                        wb2 + (size_t)(q2 * 64 + g * 16 + lr) * 288 + t * 32 + lg * 8);
                    #pragma unroll
                    for (int ms = 0; ms < 4; ++ms)
                        acc[ms][g] = mfma16(av[ms], bv, acc[ms][g]);
                }
            }
            // pool over g, bias, relu -> XS2 (bf16)
            #pragma unroll
            for (int ms = 0; ms < 4; ++ms)
                #pragma unroll
                for (int i = 0; i < 4; ++i) {
                    float v = fmaxf(fmaxf(acc[ms][0][i], acc[ms][1][i]),
                                    fmaxf(acc[ms][2][i], acc[ms][3][i]));
                    v = fmaxf(v + bcv2, 0.f);
                    if (c2 < 10) {
                        int mi = mg * 64 + ms * 16 + lg * 4 + i;
                        int k = q2 * 10 + c2;
                        XS2[mi * 128 + (((k >> 3) ^ (mi & 7)) << 3) + (k & 7)] = f2bf(v);
                    }
                }
        }
    }
    __syncthreads();

    // FC1: relu(xs2 @ W1 + b1) -> FC1 lds
    {
        const int mg2 = w >> 1, nt = w & 1;
        facc acc[2];
        acc[0] = (facc){0.f, 0.f, 0.f, 0.f};
        acc[1] = (facc){0.f, 0.f, 0.f, 0.f};
        #pragma unroll
        for (int t = 0; t < 3; ++t) {
            const bfrag bv = *(const bfrag*)(w1t + (size_t)(nt * 16 + lr) * 96 + t * 32 + lg * 8);
            #pragma unroll
            for (int ms = 0; ms < 2; ++ms) {
                int m = mg2 * 32 + ms * 16 + lr;
                bfrag av = *(const bfrag*)&XS2[m * 128 + (((t * 4 + lg) ^ (m & 7)) << 3)];
                acc[ms] = mfma16(av, bv, acc[ms]);
            }
        }
        const int jcol = nt * 16 + lr;
        const float bj = b1[jcol];
        #pragma unroll
        for (int ms = 0; ms < 2; ++ms)
            #pragma unroll
            for (int i = 0; i < 4; ++i) {
                float v = fmaxf(acc[ms][i] + bj, 0.f);
                int mi = mg2 * 32 + ms * 16 + lg * 4 + i;
                FC1[mi * 64 + (((jcol >> 3) ^ (mi & 7)) << 3) + (jcol & 7)] = f2bf(v);
            }
    }
    __syncthreads();

    // FC2: theta = (fc1 @ W2 + b2) / (1+1e-5)
    if (w < 4) {
        facc acc[2];
        acc[0] = (facc){0.f, 0.f, 0.f, 0.f};
        acc[1] = (facc){0.f, 0.f, 0.f, 0.f};
        const bfrag bv = *(const bfrag*)(w2t + (size_t)lr * 32 + lg * 8);
        #pragma unroll
        for (int ms = 0; ms < 2; ++ms) {
            int m = w * 32 + ms * 16 + lr;
            bfrag av = *(const bfrag*)&FC1[m * 64 + ((lg ^ (m & 7)) << 3)];
            acc[ms] = mfma16(av, bv, acc[ms]);
        }
        if (lr < 6) {
            const float tb = b2[lr];
            const float inv = 1.0f / (1.0f + 1e-5f);
            #pragma unroll
            for (int ms = 0; ms < 2; ++ms)
                #pragma unroll
                for (int i = 0; i < 4; ++i) {
                    long long img = blkbase + w * 32 + ms * 16 + lg * 4 + i;
                    if (img < B) theta[img * 6 + lr] = (acc[ms][i] + tb) * inv;
                }
        }
    }
}

// ---------------------------------------------------------------------------
// K3: affine grid + bilinear sample (scipy/jax reflect on integer indices)
// ---------------------------------------------------------------------------
__global__ __launch_bounds__(256, 1) void k3_sample(
    const float* __restrict__ x, const float* __restrict__ theta,
    float* __restrict__ out, int B)
{
    const long long gid = (long long)blockIdx.x * 256 + threadIdx.x;
    const long long total = (long long)B * 144;
    if (gid >= total) return;
    const int img = (int)(gid / 144);
    const int p = (int)(gid - (long long)img * 144);
    const int i = p / 12;
    const int j = p - i * 12;

    const float* th = theta + (size_t)img * 6;
    const float t0 = th[0], t1 = th[1], t2 = th[2];
    const float t3 = th[3], t4 = th[4], t5 = th[5];

    const float step = 2.0f / 11.0f;
    const float xn = -1.0f + j * step;
    const float yn = -1.0f + i * step;
    const float sx = t0 * xn + t1 * yn + t2;
    const float sy = t3 * xn + t4 * yn + t5;
    const float px = (sx + 1.0f) * 5.5f;
    const float py = (sy + 1.0f) * 5.5f;

    const float fy = floorf(py), fx = floorf(px);
    const float wy = py - fy,    wx = px - fx;
    const int ly = (int)fy, lx = (int)fx;
    const int y0 = refl12(ly), y1 = refl12(ly + 1);
    const int x0 = refl12(lx), x1 = refl12(lx + 1);

    const float* xi = x + (size_t)img * 144;
    const float v00 = xi[y0 * 12 + x0];
    const float v01 = xi[y0 * 12 + x1];
    const float v10 = xi[y1 * 12 + x0];
    const float v11 = xi[y1 * 12 + x1];

    const float r0 = v00 + wx * (v01 - v00);
    const float r1 = v10 + wx * (v11 - v10);
    out[gid] = r0 + wy * (r1 - r0);
}

extern "C" void kernel_launch(void* const* d_in, const int* in_sizes, int n_in,
                              void* d_out, int out_size, void* d_ws, size_t ws_size,
                              hipStream_t stream)
{
    const float* x   = (const float*)d_in[0];
    const float* k1w = (const float*)d_in[1];
    const float* bc1 = (const float*)d_in[2];
    const float* k2w = (const float*)d_in[3];
    const float* bc2 = (const float*)d_in[4];
    const float* W1  = (const float*)d_in[5];
    const float* b1  = (const float*)d_in[6];
    const float* W2  = (const float*)d_in[7];
    const float* b2  = (const float*)d_in[8];
    float* out = (float*)d_out;
    const int B = in_sizes[0] / 144;

    short* ws = (short*)d_ws;
    short* wb1 = ws + WB1_E;
    short* wb2 = ws + WB2_E;
    short* w1t = ws + W1T_E;
    short* w2t = ws + W2T_E;
    short* xs1 = ws + XS1_E;
    float* theta = (float*)((char*)d_ws + 707584 + (size_t)B * 576);

    hipLaunchKernelGGL(k0_build, dim3(512), dim3(256), 0, stream,
                       k1w, k2w, W1, W2, ws);

    const int nb = (B + 127) / 128;
    hipLaunchKernelGGL(k1_gemm, dim3(nb), dim3(512), 0, stream,
                       x, wb1, bc1, xs1, B);
    hipLaunchKernelGGL(k2_gemm, dim3(nb), dim3(512), 0, stream,
                       xs1, wb2, w1t, w2t, bc2, b1, b2, theta, B);

    const long long total = (long long)B * 144;
    const int nb3 = (int)((total + 255) / 256);
    hipLaunchKernelGGL(k3_sample, dim3(nb3), dim3(256), 0, stream,
                       x, theta, out, B);
}